// Round 7
// baseline (53.562 us; speedup 1.0000x reference)
//
#include <hip/hip_runtime.h>

typedef float f32x4 __attribute__((ext_vector_type(4)));
typedef short bf16x8 __attribute__((ext_vector_type(8)));
typedef __bf16 bf2 __attribute__((ext_vector_type(2)));
typedef unsigned short u16;
typedef unsigned int u32;

#define CT_ 512
#define C_ 512
#define L_ 256
#define S_ 4096
#define D_ 32
#define TILES 4

static __device__ __forceinline__ u16 f2bf(float x) {
    union { __bf16 h; u16 u; } v; v.h = (__bf16)x; return v.u;
}
static __device__ __forceinline__ u32 packbf(float a, float b) {
    union { bf2 h; u32 u; } v;
    v.h[0] = (__bf16)a; v.h[1] = (__bf16)b;
    return v.u;
}

// ---------------------------------------------------------------------------
// prep_all: blocks 0..255 convert Wv|Wk f32->bf16; blocks 256..767 transpose
// token[n][ct][l] -> tokT[n][l][ct] bf16.
__global__ __launch_bounds__(256) void prep_all(const float* __restrict__ Wv,
                                                const float* __restrict__ Wk,
                                                const float* __restrict__ token,
                                                u16* __restrict__ wbf,
                                                u16* __restrict__ tokT) {
    __shared__ float tile[32][33];
    int bx = blockIdx.x;
    int t = threadIdx.x;
    if (bx < 256) {
        int idx = (bx * 256 + t) * 8;   // 0..524287
        const float* src = (idx < 262144) ? (Wv + idx) : (Wk + (idx - 262144));
        float4 a = *(const float4*)src;
        float4 b = *(const float4*)(src + 4);
        uint4 o;
        o.x = packbf(a.x, a.y);
        o.y = packbf(a.z, a.w);
        o.z = packbf(b.x, b.y);
        o.w = packbf(b.z, b.w);
        *(uint4*)(wbf + idx) = o;
    } else {
        int b2 = bx - 256;
        int ct_t = b2 & 15, l_t = (b2 >> 4) & 7, n = b2 >> 7;
        int r = t >> 3, c4 = (t & 7) * 4;
        const float* src = token + ((size_t)n * CT_ + ct_t * 32 + r) * L_ + l_t * 32 + c4;
        float4 v = *(const float4*)src;
        tile[r][c4] = v.x; tile[r][c4 + 1] = v.y; tile[r][c4 + 2] = v.z; tile[r][c4 + 3] = v.w;
        __syncthreads();
        uint2 o;
        o.x = packbf(tile[c4][r],     tile[c4 + 1][r]);
        o.y = packbf(tile[c4 + 2][r], tile[c4 + 3][r]);
        *(uint2*)(tokT + ((size_t)n * L_ + l_t * 32 + r) * CT_ + ct_t * 32 + c4) = o;
    }
}

// ---------------------------------------------------------------------------
// kv_gemm: wave-per-block, LDS-free, 32x32 output tile per wave.
//   kv==0 -> V_ws[n][c][l] bf16
//   kv==1 -> KT_ws[n][l][c] bf16 with per-head column permutation
//            pi(d = i*16 + g*4 + r) = g*8 + i*4 + r  (matches attn's QK k-order)
// grid = 4(n) * 2(kv) * 16(c tiles of 32 = head) * 8(l tiles of 32) = 1024.
__global__ __launch_bounds__(64) void kv_gemm(const u16* __restrict__ Wv_bf,
                                              const u16* __restrict__ Wk_bf,
                                              const u16* __restrict__ tokT,
                                              const float* __restrict__ bv,
                                              const float* __restrict__ bk,
                                              u16* __restrict__ V_ws,
                                              u16* __restrict__ KT_ws) {
    int bx = blockIdx.x;
    int l_t = bx & 7, c_t = (bx >> 3) & 15, kv = (bx >> 7) & 1, n = bx >> 8;
    const u16* W = kv ? Wk_bf : Wv_bf;
    const float* bias = kv ? bk : bv;
    int c0 = c_t * 32, l0 = l_t * 32;
    int lane = threadIdx.x;
    int lr = lane & 15, g = lane >> 4;

    const f32x4 fz = {0.f, 0.f, 0.f, 0.f};
    f32x4 acc[2][2] = {{fz, fz}, {fz, fz}};

    const u16* Abase = W + (size_t)(c0 + lr) * CT_ + g * 8;
    const u16* Bbase = tokT + ((size_t)n * L_ + l0 + lr) * CT_ + g * 8;

#pragma unroll
    for (int k = 0; k < 16; ++k) {
        bf16x8 a0 = *(const bf16x8*)(Abase + k * 32);
        bf16x8 a1 = *(const bf16x8*)(Abase + (size_t)16 * CT_ + k * 32);
        bf16x8 b0 = *(const bf16x8*)(Bbase + k * 32);
        bf16x8 b1 = *(const bf16x8*)(Bbase + (size_t)16 * CT_ + k * 32);
        acc[0][0] = __builtin_amdgcn_mfma_f32_16x16x32_bf16(a0, b0, acc[0][0], 0, 0, 0);
        acc[0][1] = __builtin_amdgcn_mfma_f32_16x16x32_bf16(a0, b1, acc[0][1], 0, 0, 0);
        acc[1][0] = __builtin_amdgcn_mfma_f32_16x16x32_bf16(a1, b0, acc[1][0], 0, 0, 0);
        acc[1][1] = __builtin_amdgcn_mfma_f32_16x16x32_bf16(a1, b1, acc[1][1], 0, 0, 0);
    }

    float bb[2][4];
#pragma unroll
    for (int i = 0; i < 2; ++i)
#pragma unroll
        for (int r = 0; r < 4; ++r) bb[i][r] = bias[c0 + i * 16 + g * 4 + r];

    if (kv == 0) {
#pragma unroll
        for (int i = 0; i < 2; ++i)
#pragma unroll
            for (int jt = 0; jt < 2; ++jt) {
                int l = l0 + jt * 16 + lr;
#pragma unroll
                for (int r = 0; r < 4; ++r) {
                    int c = c0 + i * 16 + g * 4 + r;
                    V_ws[((size_t)n * C_ + c) * L_ + l] = f2bf(acc[i][jt][r] + bb[i][r]);
                }
            }
    } else {
#pragma unroll
        for (int jt = 0; jt < 2; ++jt) {
            int l = l0 + jt * 16 + lr;
#pragma unroll
            for (int i = 0; i < 2; ++i) {
                uint2 o;
                o.x = packbf(acc[i][jt][0] + bb[i][0], acc[i][jt][1] + bb[i][1]);
                o.y = packbf(acc[i][jt][2] + bb[i][2], acc[i][jt][3] + bb[i][3]);
                // permuted column: c0 + g*8 + i*4 (+r contiguous)
                *(uint2*)(KT_ws + ((size_t)n * L_ + l) * C_ + c0 + g * 8 + i * 4) = o;
            }
        }
    }
}

// ---------------------------------------------------------------------------
// attn: block = (n, head, 256-row S group = 4 tiles of 64), 256 thr = 4 waves;
// wave w owns rows s0 + w*16..+15 of each tile. K/V staged ONCE per block
// (4x amortization); inter-tile __syncthreads keeps waves lock-step so the
// per-block live L2 footprint stays small (R4's barrier-less 4-tile variant
// thrashed L2: FETCH 3x, WRITE 2.5x; R6's 2-tile+barrier stayed clean).
// Tile t+1's feature gather issued before tile t's compute. Q in registers
// via swapped mfma(Wq, feat^T); QK^T uses permuted-d k-order (K pre-permuted
// by kv_gemm); per-lane softmax (no max pass: scores ~N(0,1)); PV from
// registers via permuted l-order (V staged with matching permutation).
// grid = 1024 = exactly 4 blocks/CU, one dispatch round, no tail.
__global__ __launch_bounds__(256, 4) void attn(const float* __restrict__ feature,
                                               const float* __restrict__ Wq,
                                               const float* __restrict__ bq,
                                               const u16* __restrict__ V_ws,
                                               const u16* __restrict__ KT_ws,
                                               float* __restrict__ out) {
    __shared__ u16 KT_lds[256][40];    // K^T [l][pi(d)]  (pre-permuted cols)
    __shared__ u16 V_lds[32][296];     // V   [d][l-permuted], padded stride

    int bx = blockIdx.x;
    int sb = bx & 15, h = (bx >> 4) & 15, n = bx >> 8;
    int s_base = sb * 256;
    int t = threadIdx.x;
    int w = t >> 6, lane = t & 63, lr = lane & 15, g = lane >> 4;
    const f32x4 fz = {0.f, 0.f, 0.f, 0.f};

    // ---- stage K^T (linear copy; data pre-permuted) ----
    {
        int lq = t & 63, cb = (t >> 6) * 8;
#pragma unroll
        for (int i = 0; i < 4; ++i) {
            int l = i * 64 + lq;
            uint4 v = *(const uint4*)(KT_ws + ((size_t)n * L_ + l) * C_ + h * D_ + cb);
            *(uint4*)&KT_lds[l][cb] = v;
        }
    }
    // ---- stage V with column permutation src_chunk = ((i&1)<<2)|(i>>1) ----
    {
        int d = t & 31, cb32 = (t >> 5) * 32;
        const u16* src = V_ws + ((size_t)n * C_ + h * D_ + d) * L_ + cb32;
#pragma unroll
        for (int i = 0; i < 8; ++i) {
            int in4 = ((i & 1) << 2) | (i >> 1);
            uint2 v = *(const uint2*)(src + in4 * 4);
            *(uint2*)&V_lds[d][cb32 + i * 4] = v;
        }
    }

    // ---- Wq fragments and bias in registers (scale*log2e folded) ----
    const float scale = 0.17677669529663687f * 1.4426950408889634f; // 1/sqrt(32)*log2e
    union { u32 d[4]; bf16x8 v; } wqf[2];
#pragma unroll
    for (int dt = 0; dt < 2; ++dt) {
        const float* wsrc = Wq + ((size_t)h * D_ + dt * 16 + lr) * D_ + g * 8;
        float4 w0 = *(const float4*)wsrc;
        float4 w1 = *(const float4*)(wsrc + 4);
        wqf[dt].d[0] = packbf(w0.x * scale, w0.y * scale);
        wqf[dt].d[1] = packbf(w0.z * scale, w0.w * scale);
        wqf[dt].d[2] = packbf(w1.x * scale, w1.y * scale);
        wqf[dt].d[3] = packbf(w1.z * scale, w1.w * scale);
    }
    float bqs[2][4];
#pragma unroll
    for (int dt = 0; dt < 2; ++dt)
#pragma unroll
        for (int r = 0; r < 4; ++r)
            bqs[dt][r] = bq[h * D_ + dt * 16 + g * 4 + r] * scale;

    // ---- feature gather for tile 0 ----
    const float* fb = feature + ((size_t)n * C_ + h * D_) * S_ + s_base + w * 16 + lr;
    float f[8];
#pragma unroll
    for (int j = 0; j < 8; ++j) f[j] = fb[(size_t)(g * 8 + j) * S_];

    __syncthreads();

#pragma unroll
    for (int tile = 0; tile < TILES; ++tile) {
        int s0 = s_base + tile * 64;

        // pack current tile's feature, then issue next tile's gather
        union { u32 d[4]; bf16x8 v; } au;
#pragma unroll
        for (int k = 0; k < 4; ++k) au.d[k] = packbf(f[2 * k], f[2 * k + 1]);
        if (tile + 1 < TILES) {
#pragma unroll
            for (int j = 0; j < 8; ++j)
                f[j] = fb[(size_t)(g * 8 + j) * S_ + (tile + 1) * 64];
        }

        // ---- Q-proj: D[d][s]; lane (lr,g) reg (dt,r) = Q[dt16+g4+r][s=lr] ----
        f32x4 aq0 = __builtin_amdgcn_mfma_f32_16x16x32_bf16(wqf[0].v, au.v, fz, 0, 0, 0);
        f32x4 aq1 = __builtin_amdgcn_mfma_f32_16x16x32_bf16(wqf[1].v, au.v, fz, 0, 0, 0);
        union { u32 d[4]; bf16x8 v; } qb;
        qb.d[0] = packbf(aq0[0] + bqs[0][0], aq0[1] + bqs[0][1]);
        qb.d[1] = packbf(aq0[2] + bqs[0][2], aq0[3] + bqs[0][3]);
        qb.d[2] = packbf(aq1[0] + bqs[1][0], aq1[1] + bqs[1][1]);
        qb.d[3] = packbf(aq1[2] + bqs[1][2], aq1[3] + bqs[1][3]);

        // ---- scores: accs[lt][r] = S[l=lt16+g4+r][s = s0 + w16 + lr] ----
        f32x4 accs[16];
#pragma unroll
        for (int lt = 0; lt < 16; ++lt) {
            bf16x8 a = *(const bf16x8*)&KT_lds[lt * 16 + lr][g * 8];
            accs[lt] = __builtin_amdgcn_mfma_f32_16x16x32_bf16(a, qb.v, fz, 0, 0, 0);
        }

        // ---- softmax over l, no max pass; 4 independent sum chains ----
        float s4[4] = {0.f, 0.f, 0.f, 0.f};
#pragma unroll
        for (int lt = 0; lt < 16; ++lt) {
#pragma unroll
            for (int r = 0; r < 4; ++r) {
                float e = __builtin_amdgcn_exp2f(accs[lt][r]);
                accs[lt][r] = e;
                s4[r] += e;
            }
        }
        float sum = (s4[0] + s4[1]) + (s4[2] + s4[3]);
        sum += __shfl_xor(sum, 16, 64);
        sum += __shfl_xor(sum, 32, 64);
        float inv_own = __builtin_amdgcn_rcpf(sum);   // row s = s0 + w*16 + lr

        // ---- PV: A-frag = own accs (permuted l-order), B = permuted V ----
        f32x4 acco[2] = {fz, fz};
#pragma unroll
        for (int tc = 0; tc < 8; ++tc) {
            union { u32 d[4]; bf16x8 v; } pa;
#pragma unroll
            for (int j = 0; j < 4; ++j)
                pa.d[j] = packbf(accs[2 * tc + (j >> 1)][(j & 1) * 2],
                                 accs[2 * tc + (j >> 1)][(j & 1) * 2 + 1]);
#pragma unroll
            for (int dt = 0; dt < 2; ++dt) {
                bf16x8 vb = *(const bf16x8*)&V_lds[dt * 16 + lr][tc * 32 + g * 8];
                acco[dt] = __builtin_amdgcn_mfma_f32_16x16x32_bf16(pa.v, vb, acco[dt], 0, 0, 0);
            }
        }

        // ---- epilogue: out[s=s0+w16+g4+r][d=dt16+lr] = feat + proj*inv ----
        float inv4[4];
#pragma unroll
        for (int r = 0; r < 4; ++r)
            inv4[r] = __shfl(inv_own, (lane & 48) | (g * 4 + r), 64);
#pragma unroll
        for (int dt = 0; dt < 2; ++dt) {
            size_t off = ((size_t)n * C_ + h * D_ + dt * 16 + lr) * S_
                       + s0 + w * 16 + g * 4;
            float4 fe = *(const float4*)(feature + off);
            float4 o;
            o.x = fe.x + acco[dt][0] * inv4[0];
            o.y = fe.y + acco[dt][1] * inv4[1];
            o.z = fe.z + acco[dt][2] * inv4[2];
            o.w = fe.w + acco[dt][3] * inv4[3];
            *(float4*)(out + off) = o;
        }

        if (tile + 1 < TILES) __syncthreads();   // lock-step (L2 footprint)
    }
}

// ---------------------------------------------------------------------------
extern "C" void kernel_launch(void* const* d_in, const int* in_sizes, int n_in,
                              void* d_out, int out_size, void* d_ws, size_t ws_size,
                              hipStream_t stream) {
    const float* feature = (const float*)d_in[0];
    const float* token   = (const float*)d_in[1];
    const float* Wv      = (const float*)d_in[2];
    const float* bv      = (const float*)d_in[3];
    const float* Wk      = (const float*)d_in[4];
    const float* bk      = (const float*)d_in[5];
    const float* Wq      = (const float*)d_in[6];
    const float* bq      = (const float*)d_in[7];
    float* out = (float*)d_out;

    u16* ws16  = (u16*)d_ws;
    u16* Wv_bf = ws16;                   // 512*512
    u16* Wk_bf = Wv_bf + 262144;         // 512*512 (contiguous with Wv_bf)
    u16* tokT  = Wk_bf + 262144;         // 4*256*512
    u16* V_ws  = tokT + 524288;          // 4*512*256
    u16* KT_ws = V_ws + 524288;          // 4*256*512

    prep_all<<<dim3(768), dim3(256), 0, stream>>>(Wv, Wk, token, Wv_bf, tokT);
    kv_gemm<<<dim3(1024), dim3(64), 0, stream>>>(Wv_bf, Wk_bf, tokT, bv, bk, V_ws, KT_ws);
    attn<<<dim3(1024), dim3(256), 0, stream>>>(feature, Wq, bq, V_ws, KT_ws, out);
}

// Round 8
// 41.791 us; speedup vs baseline: 1.2817x; 1.2817x over previous
//
#include <hip/hip_runtime.h>

typedef float f32x4 __attribute__((ext_vector_type(4)));
typedef short bf16x8 __attribute__((ext_vector_type(8)));
typedef __bf16 bf2 __attribute__((ext_vector_type(2)));
typedef unsigned short u16;
typedef unsigned int u32;

#define CT_ 512
#define C_ 512
#define L_ 256
#define S_ 4096
#define D_ 32

static __device__ __forceinline__ u16 f2bf(float x) {
    union { __bf16 h; u16 u; } v; v.h = (__bf16)x; return v.u;
}
static __device__ __forceinline__ u32 packbf(float a, float b) {
    union { bf2 h; u32 u; } v;
    v.h[0] = (__bf16)a; v.h[1] = (__bf16)b;
    return v.u;
}

// ---------------------------------------------------------------------------
// prep_all: blocks 0..255 convert Wv|Wk f32->bf16; blocks 256..767 transpose
// token[n][ct][l] -> tokT[n][l][ct] bf16.
__global__ __launch_bounds__(256) void prep_all(const float* __restrict__ Wv,
                                                const float* __restrict__ Wk,
                                                const float* __restrict__ token,
                                                u16* __restrict__ wbf,
                                                u16* __restrict__ tokT) {
    __shared__ float tile[32][33];
    int bx = blockIdx.x;
    int t = threadIdx.x;
    if (bx < 256) {
        int idx = (bx * 256 + t) * 8;   // 0..524287
        const float* src = (idx < 262144) ? (Wv + idx) : (Wk + (idx - 262144));
        float4 a = *(const float4*)src;
        float4 b = *(const float4*)(src + 4);
        uint4 o;
        o.x = packbf(a.x, a.y);
        o.y = packbf(a.z, a.w);
        o.z = packbf(b.x, b.y);
        o.w = packbf(b.z, b.w);
        *(uint4*)(wbf + idx) = o;
    } else {
        int b2 = bx - 256;
        int ct_t = b2 & 15, l_t = (b2 >> 4) & 7, n = b2 >> 7;
        int r = t >> 3, c4 = (t & 7) * 4;
        const float* src = token + ((size_t)n * CT_ + ct_t * 32 + r) * L_ + l_t * 32 + c4;
        float4 v = *(const float4*)src;
        tile[r][c4] = v.x; tile[r][c4 + 1] = v.y; tile[r][c4 + 2] = v.z; tile[r][c4 + 3] = v.w;
        __syncthreads();
        uint2 o;
        o.x = packbf(tile[c4][r],     tile[c4 + 1][r]);
        o.y = packbf(tile[c4 + 2][r], tile[c4 + 3][r]);
        *(uint2*)(tokT + ((size_t)n * L_ + l_t * 32 + r) * CT_ + ct_t * 32 + c4) = o;
    }
}

// ---------------------------------------------------------------------------
// kv_gemm: wave-per-block, LDS-free, 32x32 output tile per wave.
// HEAD-MAJOR outputs so attn's staging is a contiguous 16KB copy per tensor:
//   kv==0 -> V_hs[n][h][d][perm_l(l)] bf16   (l-permutation pre-baked)
//   kv==1 -> KT_hs[n][h][l][pi(d)]    bf16   (d-permutation pre-baked)
// c-tile of 32 == one head, so c_t == h.
// grid = 4(n) * 2(kv) * 16(head) * 8(l tiles of 32) = 1024.
__global__ __launch_bounds__(64) void kv_gemm(const u16* __restrict__ Wv_bf,
                                              const u16* __restrict__ Wk_bf,
                                              const u16* __restrict__ tokT,
                                              const float* __restrict__ bv,
                                              const float* __restrict__ bk,
                                              u16* __restrict__ V_hs,
                                              u16* __restrict__ KT_hs) {
    int bx = blockIdx.x;
    int l_t = bx & 7, c_t = (bx >> 3) & 15, kv = (bx >> 7) & 1, n = bx >> 8;
    const u16* W = kv ? Wk_bf : Wv_bf;
    const float* bias = kv ? bk : bv;
    int c0 = c_t * 32, l0 = l_t * 32;
    int lane = threadIdx.x;
    int lr = lane & 15, g = lane >> 4;

    const f32x4 fz = {0.f, 0.f, 0.f, 0.f};
    f32x4 acc[2][2] = {{fz, fz}, {fz, fz}};

    const u16* Abase = W + (size_t)(c0 + lr) * CT_ + g * 8;
    const u16* Bbase = tokT + ((size_t)n * L_ + l0 + lr) * CT_ + g * 8;

#pragma unroll
    for (int k = 0; k < 16; ++k) {
        bf16x8 a0 = *(const bf16x8*)(Abase + k * 32);
        bf16x8 a1 = *(const bf16x8*)(Abase + (size_t)16 * CT_ + k * 32);
        bf16x8 b0 = *(const bf16x8*)(Bbase + k * 32);
        bf16x8 b1 = *(const bf16x8*)(Bbase + (size_t)16 * CT_ + k * 32);
        acc[0][0] = __builtin_amdgcn_mfma_f32_16x16x32_bf16(a0, b0, acc[0][0], 0, 0, 0);
        acc[0][1] = __builtin_amdgcn_mfma_f32_16x16x32_bf16(a0, b1, acc[0][1], 0, 0, 0);
        acc[1][0] = __builtin_amdgcn_mfma_f32_16x16x32_bf16(a1, b0, acc[1][0], 0, 0, 0);
        acc[1][1] = __builtin_amdgcn_mfma_f32_16x16x32_bf16(a1, b1, acc[1][1], 0, 0, 0);
    }

    float bb[2][4];
#pragma unroll
    for (int ci = 0; ci < 2; ++ci)
#pragma unroll
        for (int r = 0; r < 4; ++r) bb[ci][r] = bias[c0 + ci * 16 + g * 4 + r];

    if (kv == 0) {
        // V: d = ci*16 + g*4 + r; dst_l = l0 | inv-perm chunk | q
#pragma unroll
        for (int ci = 0; ci < 2; ++ci)
#pragma unroll
            for (int jt = 0; jt < 2; ++jt) {
                int o = jt * 16 + lr;          // within-32 l offset
                int c = o >> 2, q = o & 3;
                int ip = ((c >> 2) & 1) | ((c & 3) << 1);
                int dst_l = l0 + ip * 4 + q;
#pragma unroll
                for (int r = 0; r < 4; ++r) {
                    int d = ci * 16 + g * 4 + r;
                    V_hs[(((size_t)n * 16 + c_t) * D_ + d) * L_ + dst_l] =
                        f2bf(acc[ci][jt][r] + bb[ci][r]);
                }
            }
    } else {
        // K^T: row l, permuted col pi(d)=g*8+ci*4 (+r contiguous)
#pragma unroll
        for (int jt = 0; jt < 2; ++jt) {
            int l = l0 + jt * 16 + lr;
#pragma unroll
            for (int ci = 0; ci < 2; ++ci) {
                uint2 o;
                o.x = packbf(acc[ci][jt][0] + bb[ci][0], acc[ci][jt][1] + bb[ci][1]);
                o.y = packbf(acc[ci][jt][2] + bb[ci][2], acc[ci][jt][3] + bb[ci][3]);
                *(uint2*)(KT_hs + (((size_t)n * 16 + c_t) * L_ + l) * D_
                          + g * 8 + ci * 4) = o;
            }
        }
    }
}

// ---------------------------------------------------------------------------
// attn: block = (n, head, 128-row S group = 2 tiles of 64), 256 thr = 4 waves
// (R6 structure: 2-tile amortization is the L2-safe sweet spot; 4-tile
// thrashed L2 even with barriers — R7: FETCH 2.4x, WRITE 2.2x).
// K/V staged from HEAD-MAJOR workspace: two contiguous 16KB copies, fully
// coalesced (4x fewer TCC requests than the old strided gather). All
// permutations (K d-order, V l-order) pre-baked by kv_gemm.
// Q in registers via swapped mfma(Wq, feat^T); per-lane softmax (no max
// pass: scores ~N(0,1)); PV from registers via permuted l-order.
__global__ __launch_bounds__(256, 4) void attn(const float* __restrict__ feature,
                                               const float* __restrict__ Wq,
                                               const float* __restrict__ bq,
                                               const u16* __restrict__ V_hs,
                                               const u16* __restrict__ KT_hs,
                                               float* __restrict__ out) {
    __shared__ u16 KT_lds[256][40];    // K^T [l][pi(d)]  (pre-permuted cols)
    __shared__ u16 V_lds[32][296];     // V   [d][l-permuted], padded stride

    int bx = blockIdx.x;
    int sb = bx & 31, h = (bx >> 5) & 15, n = bx >> 9;
    int s_base = sb * 128;
    int t = threadIdx.x;
    int w = t >> 6, lane = t & 63, lr = lane & 15, g = lane >> 4;
    const f32x4 fz = {0.f, 0.f, 0.f, 0.f};

    // ---- stage K^T: contiguous 16KB copy ----
    {
        const u16* kbase = KT_hs + ((size_t)n * 16 + h) * (L_ * D_);
#pragma unroll
        for (int i = 0; i < 4; ++i) {
            uint4 v = *(const uint4*)(kbase + ((size_t)i * 256 + t) * 8);
            *(uint4*)&KT_lds[i * 64 + (t >> 2)][(t & 3) * 8] = v;
        }
    }
    // ---- stage V: contiguous 16KB copy (perm pre-baked) ----
    {
        const u16* vbase = V_hs + ((size_t)n * 16 + h) * (D_ * L_);
#pragma unroll
        for (int i = 0; i < 4; ++i) {
            uint4 v = *(const uint4*)(vbase + ((size_t)i * 256 + t) * 8);
            *(uint4*)&V_lds[i * 8 + (t >> 5)][(t & 31) * 8] = v;
        }
    }

    // ---- Wq fragments and bias in registers (scale*log2e folded) ----
    const float scale = 0.17677669529663687f * 1.4426950408889634f; // 1/sqrt(32)*log2e
    union { u32 d[4]; bf16x8 v; } wqf[2];
#pragma unroll
    for (int dt = 0; dt < 2; ++dt) {
        const float* wsrc = Wq + ((size_t)h * D_ + dt * 16 + lr) * D_ + g * 8;
        float4 w0 = *(const float4*)wsrc;
        float4 w1 = *(const float4*)(wsrc + 4);
        wqf[dt].d[0] = packbf(w0.x * scale, w0.y * scale);
        wqf[dt].d[1] = packbf(w0.z * scale, w0.w * scale);
        wqf[dt].d[2] = packbf(w1.x * scale, w1.y * scale);
        wqf[dt].d[3] = packbf(w1.z * scale, w1.w * scale);
    }
    float bqs[2][4];
#pragma unroll
    for (int dt = 0; dt < 2; ++dt)
#pragma unroll
        for (int r = 0; r < 4; ++r)
            bqs[dt][r] = bq[h * D_ + dt * 16 + g * 4 + r] * scale;

    // ---- feature gather for tile 0 ----
    const float* fb = feature + ((size_t)n * C_ + h * D_) * S_ + s_base + w * 16 + lr;
    float f[8];
#pragma unroll
    for (int j = 0; j < 8; ++j) f[j] = fb[(size_t)(g * 8 + j) * S_];

    __syncthreads();

#pragma unroll
    for (int tile = 0; tile < 2; ++tile) {
        int s0 = s_base + tile * 64;

        // pack current tile's feature, then issue next tile's gather
        union { u32 d[4]; bf16x8 v; } au;
#pragma unroll
        for (int k = 0; k < 4; ++k) au.d[k] = packbf(f[2 * k], f[2 * k + 1]);
        if (tile == 0) {
#pragma unroll
            for (int j = 0; j < 8; ++j) f[j] = fb[(size_t)(g * 8 + j) * S_ + 64];
        }

        // ---- Q-proj: D[d][s]; lane (lr,g) reg (dt,r) = Q[dt16+g4+r][s=lr] ----
        f32x4 aq0 = __builtin_amdgcn_mfma_f32_16x16x32_bf16(wqf[0].v, au.v, fz, 0, 0, 0);
        f32x4 aq1 = __builtin_amdgcn_mfma_f32_16x16x32_bf16(wqf[1].v, au.v, fz, 0, 0, 0);
        union { u32 d[4]; bf16x8 v; } qb;
        qb.d[0] = packbf(aq0[0] + bqs[0][0], aq0[1] + bqs[0][1]);
        qb.d[1] = packbf(aq0[2] + bqs[0][2], aq0[3] + bqs[0][3]);
        qb.d[2] = packbf(aq1[0] + bqs[1][0], aq1[1] + bqs[1][1]);
        qb.d[3] = packbf(aq1[2] + bqs[1][2], aq1[3] + bqs[1][3]);

        // ---- scores: accs[lt][r] = S[l=lt16+g4+r][s = s0 + w16 + lr] ----
        f32x4 accs[16];
#pragma unroll
        for (int lt = 0; lt < 16; ++lt) {
            bf16x8 a = *(const bf16x8*)&KT_lds[lt * 16 + lr][g * 8];
            accs[lt] = __builtin_amdgcn_mfma_f32_16x16x32_bf16(a, qb.v, fz, 0, 0, 0);
        }

        // ---- softmax over l, no max pass; 4 independent sum chains ----
        float s4[4] = {0.f, 0.f, 0.f, 0.f};
#pragma unroll
        for (int lt = 0; lt < 16; ++lt) {
#pragma unroll
            for (int r = 0; r < 4; ++r) {
                float e = __builtin_amdgcn_exp2f(accs[lt][r]);
                accs[lt][r] = e;
                s4[r] += e;
            }
        }
        float sum = (s4[0] + s4[1]) + (s4[2] + s4[3]);
        sum += __shfl_xor(sum, 16, 64);
        sum += __shfl_xor(sum, 32, 64);
        float inv_own = __builtin_amdgcn_rcpf(sum);   // row s = s0 + w*16 + lr

        // ---- PV: A-frag = own accs (permuted l-order), B = permuted V ----
        f32x4 acco[2] = {fz, fz};
#pragma unroll
        for (int tc = 0; tc < 8; ++tc) {
            union { u32 d[4]; bf16x8 v; } pa;
#pragma unroll
            for (int j = 0; j < 4; ++j)
                pa.d[j] = packbf(accs[2 * tc + (j >> 1)][(j & 1) * 2],
                                 accs[2 * tc + (j >> 1)][(j & 1) * 2 + 1]);
#pragma unroll
            for (int dt = 0; dt < 2; ++dt) {
                bf16x8 vb = *(const bf16x8*)&V_lds[dt * 16 + lr][tc * 32 + g * 8];
                acco[dt] = __builtin_amdgcn_mfma_f32_16x16x32_bf16(pa.v, vb, acco[dt], 0, 0, 0);
            }
        }

        // ---- epilogue: out[s=s0+w16+g4+r][d=dt16+lr] = feat + proj*inv ----
        float inv4[4];
#pragma unroll
        for (int r = 0; r < 4; ++r)
            inv4[r] = __shfl(inv_own, (lane & 48) | (g * 4 + r), 64);
#pragma unroll
        for (int dt = 0; dt < 2; ++dt) {
            size_t off = ((size_t)n * C_ + h * D_ + dt * 16 + lr) * S_
                       + s0 + w * 16 + g * 4;
            float4 fe = *(const float4*)(feature + off);
            float4 o;
            o.x = fe.x + acco[dt][0] * inv4[0];
            o.y = fe.y + acco[dt][1] * inv4[1];
            o.z = fe.z + acco[dt][2] * inv4[2];
            o.w = fe.w + acco[dt][3] * inv4[3];
            *(float4*)(out + off) = o;
        }

        if (tile == 0) __syncthreads();   // lock-step (L2 footprint)
    }
}

// ---------------------------------------------------------------------------
extern "C" void kernel_launch(void* const* d_in, const int* in_sizes, int n_in,
                              void* d_out, int out_size, void* d_ws, size_t ws_size,
                              hipStream_t stream) {
    const float* feature = (const float*)d_in[0];
    const float* token   = (const float*)d_in[1];
    const float* Wv      = (const float*)d_in[2];
    const float* bv      = (const float*)d_in[3];
    const float* Wk      = (const float*)d_in[4];
    const float* bk      = (const float*)d_in[5];
    const float* Wq      = (const float*)d_in[6];
    const float* bq      = (const float*)d_in[7];
    float* out = (float*)d_out;

    u16* ws16  = (u16*)d_ws;
    u16* Wv_bf = ws16;                   // 512*512
    u16* Wk_bf = Wv_bf + 262144;         // 512*512 (contiguous with Wv_bf)
    u16* tokT  = Wk_bf + 262144;         // 4*256*512
    u16* V_hs  = tokT + 524288;          // 4*16*32*256 head-major
    u16* KT_hs = V_hs + 524288;          // 4*16*256*32 head-major

    prep_all<<<dim3(768), dim3(256), 0, stream>>>(Wv, Wk, token, Wv_bf, tokT);
    kv_gemm<<<dim3(1024), dim3(64), 0, stream>>>(Wv_bf, Wk_bf, tokT, bv, bk, V_hs, KT_hs);
    attn<<<dim3(2048), dim3(256), 0, stream>>>(feature, Wq, bq, V_hs, KT_hs, out);
}